// Round 1
// baseline (971.102 us; speedup 1.0000x reference)
//
#include <hip/hip_runtime.h>
#include <math.h>

static constexpr int B  = 32;
static constexpr int S  = 2048;
static constexpr int D  = 512;
static constexpr int KE = 1024;   // encoder feature dim = 2*ENC_H
static constexpr int IN = 1536;   // D + KE

// ---------- kernel 0: transpose enc-part of attn_w into w2t[KE][D] ----------
__global__ void k_w2t(const float* __restrict__ attn_w, float* __restrict__ w2t) {
    int idx = blockIdx.x * 256 + threadIdx.x;      // 524288 total
    int d = idx & (D - 1);                         // fast: coalesced write
    int k = idx >> 9;
    w2t[(size_t)k * D + d] = attn_w[(size_t)d * IN + 512 + k];
}

// ---------- kernel 1: u[b][d] = hidden[b]·attn_w[d,0:512] + attn_b[d] ----------
__global__ void k_uproj(const float* __restrict__ hidden,
                        const float* __restrict__ attn_w,
                        const float* __restrict__ attn_b,
                        float* __restrict__ u) {
    int gid = blockIdx.x * 256 + threadIdx.x;      // 16384 total
    int b = gid >> 9;
    int d = gid & (D - 1);
    const float* h = hidden + b * D;
    const float* w = attn_w + (size_t)d * IN;
    float acc = attn_b[d];
    for (int k = 0; k < D; k += 4) {
        float4 hv = *(const float4*)(h + k);
        float4 wv = *(const float4*)(w + k);
        acc += hv.x * wv.x + hv.y * wv.y + hv.z * wv.z + hv.w * wv.w;
    }
    u[gid] = acc;
}

// ---------- kernel 2: scores[b][s] = v·tanh(enc@W2^T + u) + v_b ----------
static constexpr int TS = 32;   // s-positions per block
static constexpr int KT = 16;   // K tile

__global__ __launch_bounds__(256, 4) void k_scores(
    const float* __restrict__ enc, const float* __restrict__ w2t,
    const float* __restrict__ u, const float* __restrict__ v_w,
    const float* __restrict__ v_b, const int* __restrict__ lengths,
    float* __restrict__ scores)
{
    __shared__ float sA[KT][36];   // enc tile [k][s], stride 36 -> 16B-aligned rows
    __shared__ float sB[KT][D];    // W2^T tile [k][d]

    const int b  = blockIdx.y;
    const int s0 = blockIdx.x * TS;
    const int len = lengths[b];
    if (s0 >= len) return;         // masked-out tile: softmax never reads these

    const int tid = threadIdx.x;
    const int sg  = tid >> 5;      // 0..7  -> s group of 4
    const int dg  = tid & 31;      // 0..31 -> d base (x4, strided by 128)

    float acc[4][16];
    #pragma unroll
    for (int i = 0; i < 4; i++)
        #pragma unroll
        for (int j = 0; j < 16; j++) acc[i][j] = 0.f;

    const float* encb = enc + ((size_t)b * S + s0) * KE;

    for (int k0 = 0; k0 < KE; k0 += KT) {
        // stage A: 32 s x 16 k, transposed
        #pragma unroll
        for (int i = 0; i < 2; i++) {
            int e = tid + 256 * i;
            int s = e >> 4;
            int k = e & 15;
            sA[k][s] = encb[(size_t)s * KE + k0 + k];
        }
        // stage B: [k][d] direct float4 copy (coalesced, conflict-free)
        #pragma unroll
        for (int r = 0; r < 8; r++) {
            int f  = r * 256 + tid;        // float4 index 0..2047
            int k  = f >> 7;               // 0..15
            int d4 = f & 127;
            *(float4*)&sB[k][d4 * 4] =
                *(const float4*)(w2t + (size_t)(k0 + k) * D + d4 * 4);
        }
        __syncthreads();
        #pragma unroll
        for (int k = 0; k < KT; k++) {
            float4 a4 = *(const float4*)&sA[k][sg * 4];   // broadcast within wave
            float av[4] = {a4.x, a4.y, a4.z, a4.w};
            float bv[16];
            #pragma unroll
            for (int m = 0; m < 4; m++) {                 // contiguous b128 across lanes
                float4 b4 = *(const float4*)&sB[k][dg * 4 + m * 128];
                bv[m*4+0] = b4.x; bv[m*4+1] = b4.y; bv[m*4+2] = b4.z; bv[m*4+3] = b4.w;
            }
            #pragma unroll
            for (int i = 0; i < 4; i++)
                #pragma unroll
                for (int j = 0; j < 16; j++)
                    acc[i][j] += av[i] * bv[j];
        }
        __syncthreads();
    }

    // epilogue: partial score = sum_d v[d]*tanh(acc + u[b][d])
    float partial[4] = {0.f, 0.f, 0.f, 0.f};
    const float* ub = u + b * D;
    #pragma unroll
    for (int j = 0; j < 16; j++) {
        int d = dg * 4 + (j >> 2) * 128 + (j & 3);
        float uu = ub[d];
        float vd = v_w[d];
        #pragma unroll
        for (int i = 0; i < 4; i++)
            partial[i] += vd * tanhf(acc[i][j] + uu);
    }
    // reduce over dg: lanes 0..31 / 32..63 butterfly (halves never mix)
    #pragma unroll
    for (int off = 16; off >= 1; off >>= 1)
        #pragma unroll
        for (int i = 0; i < 4; i++)
            partial[i] += __shfl_xor(partial[i], off);
    if (dg == 0) {
        float vb = v_b[0];
        #pragma unroll
        for (int i = 0; i < 4; i++)
            scores[b * S + s0 + sg * 4 + i] = partial[i] + vb;
    }
}

// ---------- kernel 3: masked softmax over s < len ----------
__global__ void k_softmax(const float* __restrict__ scores,
                          const int* __restrict__ lengths,
                          float* __restrict__ energy) {
    const int b = blockIdx.x;
    const int len = lengths[b];
    const int tid = threadIdx.x;
    const int lane = tid & 63, wave = tid >> 6;
    __shared__ float red[4];
    const float* sc = scores + b * S;

    float m = -INFINITY;
    for (int s = tid; s < len; s += 256) m = fmaxf(m, sc[s]);
    #pragma unroll
    for (int off = 32; off >= 1; off >>= 1) m = fmaxf(m, __shfl_xor(m, off));
    if (lane == 0) red[wave] = m;
    __syncthreads();
    m = fmaxf(fmaxf(red[0], red[1]), fmaxf(red[2], red[3]));
    __syncthreads();

    float sum = 0.f;
    for (int s = tid; s < len; s += 256) sum += __expf(sc[s] - m);
    #pragma unroll
    for (int off = 32; off >= 1; off >>= 1) sum += __shfl_xor(sum, off);
    if (lane == 0) red[wave] = sum;
    __syncthreads();
    float inv = 1.f / (red[0] + red[1] + red[2] + red[3]);

    for (int s = tid; s < len; s += 256) energy[b * S + s] = __expf(sc[s] - m) * inv;
}

// ---------- kernel 4: context[b][e] = sum_s energy[b][s]*enc[b][s][e] ----------
__global__ void k_context(const float* __restrict__ enc,
                          const float* __restrict__ energy,
                          const int* __restrict__ lengths,
                          float* __restrict__ out) {
    const int b = blockIdx.y;
    const int len = lengths[b];
    const int s0 = blockIdx.x * 128;
    if (s0 >= len) return;
    const int s1 = min(s0 + 128, len);
    const int tid = threadIdx.x;                 // 256 threads x float4 = 1024 e
    const float4* encb = (const float4*)(enc + (size_t)b * S * KE);
    const float* en = energy + b * S;
    float4 acc = {0.f, 0.f, 0.f, 0.f};
    for (int s = s0; s < s1; s++) {
        float w = en[s];
        float4 v = encb[(size_t)s * 256 + tid];
        acc.x += w * v.x; acc.y += w * v.y; acc.z += w * v.z; acc.w += w * v.w;
    }
    float* o = out + b * KE + tid * 4;
    atomicAdd(o + 0, acc.x);
    atomicAdd(o + 1, acc.y);
    atomicAdd(o + 2, acc.z);
    atomicAdd(o + 3, acc.w);
}

extern "C" void kernel_launch(void* const* d_in, const int* in_sizes, int n_in,
                              void* d_out, int out_size, void* d_ws, size_t ws_size,
                              hipStream_t stream) {
    const float* enc    = (const float*)d_in[0];
    const float* hidden = (const float*)d_in[1];
    const int*   lengths= (const int*)d_in[2];
    const float* attn_w = (const float*)d_in[3];
    const float* attn_b = (const float*)d_in[4];
    const float* v_w    = (const float*)d_in[5];
    const float* v_b    = (const float*)d_in[6];
    float* out = (float*)d_out;

    // workspace layout (fp32 elements): total ~2.7 MB
    float* ws     = (float*)d_ws;
    float* u      = ws;                 // B*D     = 16384
    float* scores = u + B * D;          // B*S     = 65536
    float* energy = scores + B * S;     // B*S     = 65536
    float* w2t    = energy + B * S;     // KE*D    = 524288

    hipMemsetAsync(d_out, 0, (size_t)out_size * sizeof(float), stream);
    k_w2t   <<<dim3((KE * D) / 256), 256, 0, stream>>>(attn_w, w2t);
    k_uproj <<<dim3((B * D) / 256), 256, 0, stream>>>(hidden, attn_w, attn_b, u);
    k_scores<<<dim3(S / TS, B), 256, 0, stream>>>(enc, w2t, u, v_w, v_b, lengths, scores);
    k_softmax<<<dim3(B), 256, 0, stream>>>(scores, lengths, energy);
    k_context<<<dim3(16, B), 256, 0, stream>>>(enc, energy, lengths, out);
}

// Round 2
// 657.208 us; speedup vs baseline: 1.4776x; 1.4776x over previous
//
#include <hip/hip_runtime.h>
#include <math.h>

typedef __attribute__((ext_vector_type(8))) short short8;
typedef __attribute__((ext_vector_type(16))) float f32x16;

static constexpr int B  = 32;
static constexpr int S  = 2048;
static constexpr int D  = 512;
static constexpr int KE = 1024;   // encoder feature dim = 2*ENC_H
static constexpr int IN = 1536;   // D + KE

// fp32 -> bf16 round-to-nearest-even (bit trick)
__device__ __forceinline__ short f2bf(float f) {
    unsigned u = __builtin_bit_cast(unsigned, f);
    u = u + 0x7FFFu + ((u >> 16) & 1u);
    return (short)(u >> 16);
}

// fast tanh via exp: (e^2x - 1)/(e^2x + 1)
__device__ __forceinline__ float tanh_fast(float x) {
    float e = __expf(2.0f * x);
    return (e - 1.0f) * __builtin_amdgcn_rcpf(e + 1.0f);
}

// ---------- kernel 0: pack enc-part of attn_w into bf16 MFMA-B-fragment order ----------
// element (d, k) -> frag16B index ((k>>4)*16 + (d>>5))*64 + (d&31) + ((k>>3)&1)*32, slot j=k&7
// so a B-frag load for (k16, ntile) is 64 lanes x contiguous 16B = 1KB coalesced.
__global__ void k_w2t(const float* __restrict__ attn_w, unsigned short* __restrict__ Bf) {
    int idx = blockIdx.x * 256 + threadIdx.x;      // 524288 total
    int d = idx >> 10;
    int k = idx & 1023;
    float v = attn_w[(size_t)d * IN + 512 + k];
    int off = ((k >> 4) * 16 + (d >> 5)) * 64 + (d & 31) + ((k >> 3) & 1) * 32;
    Bf[(size_t)off * 8 + (k & 7)] = (unsigned short)f2bf(v);
}

// ---------- kernel 1: u[b][d] = hidden[b]·attn_w[d,0:512] + attn_b[d] ----------
__global__ void k_uproj(const float* __restrict__ hidden,
                        const float* __restrict__ attn_w,
                        const float* __restrict__ attn_b,
                        float* __restrict__ u) {
    int gid = blockIdx.x * 256 + threadIdx.x;      // 16384 total
    int b = gid >> 9;
    int d = gid & (D - 1);
    const float* h = hidden + b * D;
    const float* w = attn_w + (size_t)d * IN;
    float acc = attn_b[d];
    for (int k = 0; k < D; k += 4) {
        float4 hv = *(const float4*)(h + k);
        float4 wv = *(const float4*)(w + k);
        acc += hv.x * wv.x + hv.y * wv.y + hv.z * wv.z + hv.w * wv.w;
    }
    u[gid] = acc;
}

// ---------- kernel 2: scores via bf16 MFMA ----------
// block: 64 s x 512 d. 4 waves; wave w owns d in [w*128, w*128+128).
// A (enc) staged per-wave into private dbuf LDS (no __syncthreads in K-loop).
// B frags read straight from global (L2-resident, coalesced 1KB per frag).
__global__ __launch_bounds__(256, 2) void k_scores(
    const float* __restrict__ enc, const unsigned short* __restrict__ Bfrag,
    const float* __restrict__ u, const float* __restrict__ v_w,
    const float* __restrict__ v_b, const int* __restrict__ lengths,
    float* __restrict__ scores)
{
    __shared__ short8 ldsA[4][2][256];   // [wave][dbuf][(t*2+mt)*64 + lane] : 32KB
    __shared__ float sPart[4][64];

    const int b   = blockIdx.y;
    const int s0  = blockIdx.x * 64;
    const int len = lengths[b];
    if (s0 >= len) return;

    const int tid = threadIdx.x;
    const int w   = tid >> 6;     // wave 0..3
    const int l   = tid & 63;     // lane

    const float*  encb = enc + ((size_t)b * S + s0) * KE;
    const short8* Bf   = (const short8*)Bfrag;

    f32x16 acc[2][4];
    #pragma unroll
    for (int mt = 0; mt < 2; mt++)
        #pragma unroll
        for (int jt = 0; jt < 4; jt++)
            #pragma unroll
            for (int e = 0; e < 16; e++) acc[mt][jt][e] = 0.f;

    #pragma unroll 1
    for (int k0 = 0; k0 < KE; k0 += 32) {
        const int buf = (k0 >> 5) & 1;
        // ---- per-wave A staging: 64m x 32k fp32 -> bf16, swizzled to frag order ----
        #pragma unroll
        for (int r = 0; r < 4; r++) {
            int c  = l + 64 * r;          // chunk id
            int m  = c >> 2;
            int k8 = c & 3;
            const float* src = encb + (size_t)m * KE + k0 + k8 * 8;
            float4 f0 = *(const float4*)src;
            float4 f1 = *(const float4*)(src + 4);
            short8 p;
            p[0] = f2bf(f0.x); p[1] = f2bf(f0.y); p[2] = f2bf(f0.z); p[3] = f2bf(f0.w);
            p[4] = f2bf(f1.x); p[5] = f2bf(f1.y); p[6] = f2bf(f1.z); p[7] = f2bf(f1.w);
            int t = k8 >> 1, half = k8 & 1, mt = m >> 5;
            ldsA[w][buf][(t * 2 + mt) * 64 + (m & 31) + (half << 5)] = p;
        }
        // ---- compute: 2 K16-steps x 4 n-tiles x 2 m-tiles ----
        #pragma unroll
        for (int t = 0; t < 2; t++) {
            short8 a0 = ldsA[w][buf][(t * 2 + 0) * 64 + l];
            short8 a1 = ldsA[w][buf][(t * 2 + 1) * 64 + l];
            int k16 = (k0 >> 4) + t;
            #pragma unroll
            for (int jt = 0; jt < 4; jt++) {
                short8 bf = Bf[(size_t)((k16 * 16 + w * 4 + jt) * 64 + l)];
                acc[0][jt] = __builtin_amdgcn_mfma_f32_32x32x16_bf16(a0, bf, acc[0][jt], 0, 0, 0);
                acc[1][jt] = __builtin_amdgcn_mfma_f32_32x32x16_bf16(a1, bf, acc[1][jt], 0, 0, 0);
            }
        }
    }

    // ---- epilogue: score_part = sum_d v[d]*tanh(pre + u[d]) ----
    // C/D layout (32x32): col = lane&31, row = (reg&3) + 8*(reg>>2) + 4*(lane>>5)
    float vv[4], uu[4];
    const float* ub = u + b * D;
    #pragma unroll
    for (int jt = 0; jt < 4; jt++) {
        int d = w * 128 + jt * 32 + (l & 31);
        vv[jt] = v_w[d];
        uu[jt] = ub[d];
    }
    float red[2][16];
    #pragma unroll
    for (int mt = 0; mt < 2; mt++)
        #pragma unroll
        for (int r = 0; r < 16; r++) {
            float s = 0.f;
            #pragma unroll
            for (int jt = 0; jt < 4; jt++)
                s += vv[jt] * tanh_fast(acc[mt][jt][r] + uu[jt]);
            red[mt][r] = s;
        }
    // butterfly over the 32 lanes sharing each row-half (bits 0..4)
    #pragma unroll
    for (int off = 16; off >= 1; off >>= 1)
        #pragma unroll
        for (int mt = 0; mt < 2; mt++)
            #pragma unroll
            for (int r = 0; r < 16; r++)
                red[mt][r] += __shfl_xor(red[mt][r], off);
    if ((l & 31) == 0) {
        int hb = (l >> 5) * 4;
        #pragma unroll
        for (int mt = 0; mt < 2; mt++)
            #pragma unroll
            for (int r = 0; r < 16; r++)
                sPart[w][mt * 32 + (r & 3) + 8 * (r >> 2) + hb] = red[mt][r];
    }
    __syncthreads();
    if (tid < 64)
        scores[b * S + s0 + tid] =
            sPart[0][tid] + sPart[1][tid] + sPart[2][tid] + sPart[3][tid] + v_b[0];
}

// ---------- kernel 3: masked softmax over s < len ----------
__global__ void k_softmax(const float* __restrict__ scores,
                          const int* __restrict__ lengths,
                          float* __restrict__ energy) {
    const int b = blockIdx.x;
    const int len = lengths[b];
    const int tid = threadIdx.x;
    const int lane = tid & 63, wave = tid >> 6;
    __shared__ float red[4];
    const float* sc = scores + b * S;

    float m = -INFINITY;
    for (int s = tid; s < len; s += 256) m = fmaxf(m, sc[s]);
    #pragma unroll
    for (int off = 32; off >= 1; off >>= 1) m = fmaxf(m, __shfl_xor(m, off));
    if (lane == 0) red[wave] = m;
    __syncthreads();
    m = fmaxf(fmaxf(red[0], red[1]), fmaxf(red[2], red[3]));
    __syncthreads();

    float sum = 0.f;
    for (int s = tid; s < len; s += 256) sum += __expf(sc[s] - m);
    #pragma unroll
    for (int off = 32; off >= 1; off >>= 1) sum += __shfl_xor(sum, off);
    if (lane == 0) red[wave] = sum;
    __syncthreads();
    float inv = 1.f / (red[0] + red[1] + red[2] + red[3]);

    for (int s = tid; s < len; s += 256) energy[b * S + s] = __expf(sc[s] - m) * inv;
}

// ---------- kernel 4: context[b][e] = sum_s energy[b][s]*enc[b][s][e] ----------
__global__ void k_context(const float* __restrict__ enc,
                          const float* __restrict__ energy,
                          const int* __restrict__ lengths,
                          float* __restrict__ out) {
    const int b = blockIdx.y;
    const int len = lengths[b];
    const int s0 = blockIdx.x * 128;
    if (s0 >= len) return;
    const int s1 = min(s0 + 128, len);
    const int tid = threadIdx.x;                 // 256 threads x float4 = 1024 e
    const float4* encb = (const float4*)(enc + (size_t)b * S * KE);
    const float* en = energy + b * S;
    float4 acc = {0.f, 0.f, 0.f, 0.f};
    for (int s = s0; s < s1; s++) {
        float w = en[s];
        float4 v = encb[(size_t)s * 256 + tid];
        acc.x += w * v.x; acc.y += w * v.y; acc.z += w * v.z; acc.w += w * v.w;
    }
    float* o = out + b * KE + tid * 4;
    atomicAdd(o + 0, acc.x);
    atomicAdd(o + 1, acc.y);
    atomicAdd(o + 2, acc.z);
    atomicAdd(o + 3, acc.w);
}

extern "C" void kernel_launch(void* const* d_in, const int* in_sizes, int n_in,
                              void* d_out, int out_size, void* d_ws, size_t ws_size,
                              hipStream_t stream) {
    const float* enc    = (const float*)d_in[0];
    const float* hidden = (const float*)d_in[1];
    const int*   lengths= (const int*)d_in[2];
    const float* attn_w = (const float*)d_in[3];
    const float* attn_b = (const float*)d_in[4];
    const float* v_w    = (const float*)d_in[5];
    const float* v_b    = (const float*)d_in[6];
    float* out = (float*)d_out;

    // workspace layout (fp32 elements)
    float* ws     = (float*)d_ws;
    float* u      = ws;                     // 16384 floats
    float* scores = u + B * D;              // 65536 floats
    float* energy = scores + B * S;         // 65536 floats
    unsigned short* Bf = (unsigned short*)(energy + B * S);  // 524288 bf16 = 1MB, 16B-aligned

    hipMemsetAsync(d_out, 0, (size_t)out_size * sizeof(float), stream);
    k_w2t   <<<dim3((KE * D) / 256), 256, 0, stream>>>(attn_w, Bf);
    k_uproj <<<dim3((B * D) / 256), 256, 0, stream>>>(hidden, attn_w, attn_b, u);
    k_scores<<<dim3(S / 64, B), 256, 0, stream>>>(enc, Bf, u, v_w, v_b, lengths, scores);
    k_softmax<<<dim3(B), 256, 0, stream>>>(scores, lengths, energy);
    k_context<<<dim3(16, B), 256, 0, stream>>>(enc, energy, lengths, out);
}

// Round 4
// 570.198 us; speedup vs baseline: 1.7031x; 1.1526x over previous
//
#include <hip/hip_runtime.h>
#include <hip/hip_bf16.h>
#include <math.h>

typedef __attribute__((ext_vector_type(8))) short short8;
typedef __attribute__((ext_vector_type(4))) unsigned uint4v;
typedef __attribute__((ext_vector_type(16))) float f32x16;

static constexpr int B  = 32;
static constexpr int S  = 2048;
static constexpr int D  = 512;
static constexpr int KE = 1024;   // encoder feature dim = 2*ENC_H
static constexpr int IN = 1536;   // D + KE

__device__ __forceinline__ unsigned pk2(float lo, float hi) {
    __hip_bfloat162 t = __float22bfloat162_rn(make_float2(lo, hi));
    unsigned u;
    __builtin_memcpy(&u, &t, 4);
    return u;
}

// pack 8 fp32 -> short8 of bf16 via packed cvt (v_cvt_pk_bf16_f32 on gfx950)
__device__ __forceinline__ short8 pack8(float4 f0, float4 f1) {
    uint4v u;
    u[0] = pk2(f0.x, f0.y);
    u[1] = pk2(f0.z, f0.w);
    u[2] = pk2(f1.x, f1.y);
    u[3] = pk2(f1.z, f1.w);
    short8 r;
    __builtin_memcpy(&r, &u, 16);
    return r;
}

// fast tanh via exp: (e^2x - 1)/(e^2x + 1)
__device__ __forceinline__ float tanh_fast(float x) {
    float e = __expf(2.0f * x);
    return (e - 1.0f) * __builtin_amdgcn_rcpf(e + 1.0f);
}

// ---------- kernel 0: pack enc-part of attn_w into bf16 MFMA-B-fragment order ----------
// Bf layout: element (d,k) -> short8 index
//   ((k>>4)*16 + (d>>5))*64 + (d&31) + ((k>>3)&1)*32 , slot j = k&7
// This kernel iterates the OUTPUT index so writes are fully coalesced.
__global__ void k_w2t(const float* __restrict__ attn_w, unsigned short* __restrict__ Bf) {
    int o = blockIdx.x * 256 + threadIdx.x;   // short8 index, 65536 total
    int l6  = o & 63;
    int grp = o >> 6;
    int d = (grp & 15) * 32 + (l6 & 31);
    int k = (grp >> 4) * 16 + (l6 >> 5) * 8;
    const float* src = attn_w + (size_t)d * IN + 512 + k;
    float4 f0 = *(const float4*)src;
    float4 f1 = *(const float4*)(src + 4);
    ((short8*)Bf)[o] = pack8(f0, f1);
}

// ---------- kernel 1: u[b][d] = hidden[b]·attn_w[d,0:512] + attn_b[d] ----------
__global__ void k_uproj(const float* __restrict__ hidden,
                        const float* __restrict__ attn_w,
                        const float* __restrict__ attn_b,
                        float* __restrict__ u) {
    int gid = blockIdx.x * 256 + threadIdx.x;      // 16384 total
    int b = gid >> 9;
    int d = gid & (D - 1);
    const float* h = hidden + b * D;
    const float* w = attn_w + (size_t)d * IN;
    float acc = attn_b[d];
    for (int k = 0; k < D; k += 4) {
        float4 hv = *(const float4*)(h + k);
        float4 wv = *(const float4*)(w + k);
        acc += hv.x * wv.x + hv.y * wv.y + hv.z * wv.z + hv.w * wv.w;
    }
    u[gid] = acc;
}

// ---------- kernel 2: scores via bf16 MFMA, A + B direct from global ----------
// block: 64 s x 512 d. wave w owns d-slice [w*128,(w+1)*128): 2 m-tiles x 4 n-tiles.
// A-frag (32x32x16): lane l holds row m=l&31, k = (l>>5)*8 + j  -> 2 float4 / mt / k16.
// No LDS in the K-loop; reg-level pipeline: A prefetch depth 2, B depth 1.
#define LOADA(K, DST) do {                                     \
    const float* _p0 = a0p + (K) * 16;                         \
    const float* _p1 = a1p + (K) * 16;                         \
    DST[0][0] = *(const float4*)_p0;                           \
    DST[0][1] = *(const float4*)(_p0 + 4);                     \
    DST[1][0] = *(const float4*)_p1;                           \
    DST[1][1] = *(const float4*)(_p1 + 4);                     \
} while (0)

#define LOADB(K, DST) do {                                     \
    _Pragma("unroll")                                          \
    for (int _jt = 0; _jt < 4; _jt++)                          \
        DST[_jt] = bb[(size_t)(K) * 1024 + _jt * 64];          \
} while (0)

__global__ __launch_bounds__(256, 2) void k_scores(
    const float* __restrict__ enc, const unsigned short* __restrict__ Bfrag,
    const float* __restrict__ u, const float* __restrict__ v_w,
    const float* __restrict__ v_b, const int* __restrict__ lengths,
    float* __restrict__ scores)
{
    __shared__ float sPart[4][64];

    const int b   = blockIdx.y;
    const int s0  = blockIdx.x * 64;
    const int len = lengths[b];
    if (s0 >= len) return;

    const int tid = threadIdx.x;
    const int w   = tid >> 6;     // wave 0..3
    const int l   = tid & 63;     // lane

    const float* a0p = enc + ((size_t)b * S + s0 + (l & 31)) * KE + ((l >> 5) << 3);
    const float* a1p = a0p + (size_t)32 * KE;
    const short8* bb = (const short8*)Bfrag + (w * 4) * 64 + l;

    f32x16 acc[2][4];
    #pragma unroll
    for (int mt = 0; mt < 2; mt++)
        #pragma unroll
        for (int jt = 0; jt < 4; jt++)
            #pragma unroll
            for (int e = 0; e < 16; e++) acc[mt][jt][e] = 0.f;

    float4 pa[2][2][2];   // [parity][mt][half]
    short8 pb[4];
    LOADA(0, pa[0]);
    LOADA(1, pa[1]);
    LOADB(0, pb);

    #pragma unroll 2
    for (int k16 = 0; k16 < 64; ++k16) {
        const int par = k16 & 1;
        short8 a0 = pack8(pa[par][0][0], pa[par][0][1]);
        short8 a1 = pack8(pa[par][1][0], pa[par][1][1]);
        // prefetch A for k16+2 (reuses just-consumed regs), B for k16+1
        LOADA((k16 + 2) & 63, pa[par]);
        short8 nb[4];
        LOADB((k16 + 1) & 63, nb);
        #pragma unroll
        for (int jt = 0; jt < 4; jt++) {
            acc[0][jt] = __builtin_amdgcn_mfma_f32_32x32x16_bf16(a0, pb[jt], acc[0][jt], 0, 0, 0);
            acc[1][jt] = __builtin_amdgcn_mfma_f32_32x32x16_bf16(a1, pb[jt], acc[1][jt], 0, 0, 0);
        }
        #pragma unroll
        for (int jt = 0; jt < 4; jt++) pb[jt] = nb[jt];
    }

    // ---- epilogue: score_part = sum_d v[d]*tanh(pre + u[d]) ----
    // C/D layout (32x32): col = lane&31, row = (reg&3) + 8*(reg>>2) + 4*(lane>>5)
    float vv[4], uu[4];
    const float* ub = u + b * D;
    #pragma unroll
    for (int jt = 0; jt < 4; jt++) {
        int d = w * 128 + jt * 32 + (l & 31);
        vv[jt] = v_w[d];
        uu[jt] = ub[d];
    }
    float red[2][16];
    #pragma unroll
    for (int mt = 0; mt < 2; mt++)
        #pragma unroll
        for (int r = 0; r < 16; r++) {
            float s = 0.f;
            #pragma unroll
            for (int jt = 0; jt < 4; jt++)
                s += vv[jt] * tanh_fast(acc[mt][jt][r] + uu[jt]);
            red[mt][r] = s;
        }
    #pragma unroll
    for (int off = 16; off >= 1; off >>= 1)
        #pragma unroll
        for (int mt = 0; mt < 2; mt++)
            #pragma unroll
            for (int r = 0; r < 16; r++)
                red[mt][r] += __shfl_xor(red[mt][r], off);
    if ((l & 31) == 0) {
        int hb = (l >> 5) * 4;
        #pragma unroll
        for (int mt = 0; mt < 2; mt++)
            #pragma unroll
            for (int r = 0; r < 16; r++)
                sPart[w][mt * 32 + (r & 3) + 8 * (r >> 2) + hb] = red[mt][r];
    }
    __syncthreads();
    if (tid < 64)
        scores[b * S + s0 + tid] =
            sPart[0][tid] + sPart[1][tid] + sPart[2][tid] + sPart[3][tid] + v_b[0];
}

// ---------- kernel 3: masked softmax over s < len ----------
__global__ void k_softmax(const float* __restrict__ scores,
                          const int* __restrict__ lengths,
                          float* __restrict__ energy) {
    const int b = blockIdx.x;
    const int len = lengths[b];
    const int tid = threadIdx.x;
    const int lane = tid & 63, wave = tid >> 6;
    __shared__ float red[4];
    const float* sc = scores + b * S;

    float m = -INFINITY;
    for (int s = tid; s < len; s += 256) m = fmaxf(m, sc[s]);
    #pragma unroll
    for (int off = 32; off >= 1; off >>= 1) m = fmaxf(m, __shfl_xor(m, off));
    if (lane == 0) red[wave] = m;
    __syncthreads();
    m = fmaxf(fmaxf(red[0], red[1]), fmaxf(red[2], red[3]));
    __syncthreads();

    float sum = 0.f;
    for (int s = tid; s < len; s += 256) sum += __expf(sc[s] - m);
    #pragma unroll
    for (int off = 32; off >= 1; off >>= 1) sum += __shfl_xor(sum, off);
    if (lane == 0) red[wave] = sum;
    __syncthreads();
    float inv = 1.f / (red[0] + red[1] + red[2] + red[3]);

    for (int s = tid; s < len; s += 256) energy[b * S + s] = __expf(sc[s] - m) * inv;
}

// ---------- kernel 4: context[b][e] = sum_s energy[b][s]*enc[b][s][e] ----------
__global__ void k_context(const float* __restrict__ enc,
                          const float* __restrict__ energy,
                          const int* __restrict__ lengths,
                          float* __restrict__ out) {
    const int b = blockIdx.y;
    const int len = lengths[b];
    const int s0 = blockIdx.x * 128;
    if (s0 >= len) return;
    const int s1 = min(s0 + 128, len);
    const int tid = threadIdx.x;                 // 256 threads x float4 = 1024 e
    const float4* encb = (const float4*)(enc + (size_t)b * S * KE);
    const float* en = energy + b * S;
    float4 acc[4];
    #pragma unroll
    for (int i = 0; i < 4; i++) acc[i] = make_float4(0.f, 0.f, 0.f, 0.f);
    int s = s0;
    for (; s + 4 <= s1; s += 4) {
        #pragma unroll
        for (int i = 0; i < 4; i++) {
            float wgt = en[s + i];
            float4 v = encb[(size_t)(s + i) * 256 + tid];
            acc[i].x += wgt * v.x; acc[i].y += wgt * v.y;
            acc[i].z += wgt * v.z; acc[i].w += wgt * v.w;
        }
    }
    for (; s < s1; s++) {
        float wgt = en[s];
        float4 v = encb[(size_t)s * 256 + tid];
        acc[0].x += wgt * v.x; acc[0].y += wgt * v.y;
        acc[0].z += wgt * v.z; acc[0].w += wgt * v.w;
    }
    float4 a = make_float4(acc[0].x + acc[1].x + acc[2].x + acc[3].x,
                           acc[0].y + acc[1].y + acc[2].y + acc[3].y,
                           acc[0].z + acc[1].z + acc[2].z + acc[3].z,
                           acc[0].w + acc[1].w + acc[2].w + acc[3].w);
    float* o = out + b * KE + tid * 4;
    atomicAdd(o + 0, a.x);
    atomicAdd(o + 1, a.y);
    atomicAdd(o + 2, a.z);
    atomicAdd(o + 3, a.w);
}

extern "C" void kernel_launch(void* const* d_in, const int* in_sizes, int n_in,
                              void* d_out, int out_size, void* d_ws, size_t ws_size,
                              hipStream_t stream) {
    const float* enc    = (const float*)d_in[0];
    const float* hidden = (const float*)d_in[1];
    const int*   lengths= (const int*)d_in[2];
    const float* attn_w = (const float*)d_in[3];
    const float* attn_b = (const float*)d_in[4];
    const float* v_w    = (const float*)d_in[5];
    const float* v_b    = (const float*)d_in[6];
    float* out = (float*)d_out;

    // workspace layout (fp32 elements)
    float* ws     = (float*)d_ws;
    float* u      = ws;                     // 16384 floats
    float* scores = u + B * D;              // 65536 floats
    float* energy = scores + B * S;         // 65536 floats
    unsigned short* Bf = (unsigned short*)(energy + B * S);  // 524288 bf16 = 1MB, 16B-aligned

    (void)hipMemsetAsync(d_out, 0, (size_t)out_size * sizeof(float), stream);
    k_w2t   <<<dim3(65536 / 256), 256, 0, stream>>>(attn_w, Bf);
    k_uproj <<<dim3((B * D) / 256), 256, 0, stream>>>(hidden, attn_w, attn_b, u);
    k_scores<<<dim3(S / 64, B), 256, 0, stream>>>(enc, Bf, u, v_w, v_b, lengths, scores);
    k_softmax<<<dim3(B), 256, 0, stream>>>(scores, lengths, energy);
    k_context<<<dim3(16, B), 256, 0, stream>>>(enc, energy, lengths, out);
}

// Round 5
// 525.827 us; speedup vs baseline: 1.8468x; 1.0844x over previous
//
#include <hip/hip_runtime.h>
#include <hip/hip_bf16.h>
#include <math.h>

typedef __attribute__((ext_vector_type(8))) short short8;
typedef __attribute__((ext_vector_type(4))) unsigned uint4v;
typedef __attribute__((ext_vector_type(16))) float f32x16;

static constexpr int B  = 32;
static constexpr int S  = 2048;
static constexpr int D  = 512;
static constexpr int KE = 1024;   // encoder feature dim = 2*ENC_H
static constexpr int IN = 1536;   // D + KE

__device__ __forceinline__ unsigned pk2(float lo, float hi) {
    __hip_bfloat162 t = __float22bfloat162_rn(make_float2(lo, hi));
    unsigned u;
    __builtin_memcpy(&u, &t, 4);
    return u;
}

// pack 8 fp32 -> short8 of bf16 via packed cvt (v_cvt_pk_bf16_f32 on gfx950)
__device__ __forceinline__ short8 pack8(float4 f0, float4 f1) {
    uint4v u;
    u[0] = pk2(f0.x, f0.y);
    u[1] = pk2(f0.z, f0.w);
    u[2] = pk2(f1.x, f1.y);
    u[3] = pk2(f1.z, f1.w);
    short8 r;
    __builtin_memcpy(&r, &u, 16);
    return r;
}

// fast tanh via exp: (e^2x - 1)/(e^2x + 1)
__device__ __forceinline__ float tanh_fast(float x) {
    float e = __expf(2.0f * x);
    return (e - 1.0f) * __builtin_amdgcn_rcpf(e + 1.0f);
}

// ---------- kernel 0: fused prep ----------
// blocks [0,256): pack enc-part of attn_w into bf16 MFMA-B-fragment order
//   Bf layout: element (d,k) -> short8 index
//   ((k>>4)*16 + (d>>5))*64 + (d&31) + ((k>>3)&1)*32 , slot j = k&7
// blocks [256,320): u[b][d] = hidden[b]·attn_w[d,0:512] + attn_b[d]
__global__ void k_prep(const float* __restrict__ attn_w,
                       const float* __restrict__ hidden,
                       const float* __restrict__ attn_b,
                       unsigned short* __restrict__ Bf,
                       float* __restrict__ u) {
    if (blockIdx.x < 256) {
        int o = blockIdx.x * 256 + threadIdx.x;   // short8 index, 65536 total
        int l6  = o & 63;
        int grp = o >> 6;
        int d = (grp & 15) * 32 + (l6 & 31);
        int k = (grp >> 4) * 16 + (l6 >> 5) * 8;
        const float* src = attn_w + (size_t)d * IN + 512 + k;
        float4 f0 = *(const float4*)src;
        float4 f1 = *(const float4*)(src + 4);
        ((short8*)Bf)[o] = pack8(f0, f1);
    } else {
        int gid = (blockIdx.x - 256) * 256 + threadIdx.x;   // 16384 total
        int b = gid >> 9;
        int d = gid & (D - 1);
        const float* h = hidden + b * D;
        const float* w = attn_w + (size_t)d * IN;
        float acc = attn_b[d];
        for (int k = 0; k < D; k += 4) {
            float4 hv = *(const float4*)(h + k);
            float4 wv = *(const float4*)(w + k);
            acc += hv.x * wv.x + hv.y * wv.y + hv.z * wv.z + hv.w * wv.w;
        }
        u[gid] = acc;
    }
}

// ---------- kernel 2: scores via bf16 MFMA, A + B direct from global ----------
// block: 64 s x 512 d. wave w owns d-slice [w*128,(w+1)*128): 2 m-tiles x 4 n-tiles.
// A-frag (32x32x16): lane l holds row m=l&31, k = (l>>5)*8 + j  -> 2 float4 / mt / k16.
// No LDS in the K-loop. Register pipeline: A prefetch distance 4, B distance 2.
#define LOADA(K, DST) do {                                     \
    const float* _p0 = a0p + (K) * 16;                         \
    const float* _p1 = a1p + (K) * 16;                         \
    DST[0][0] = *(const float4*)_p0;                           \
    DST[0][1] = *(const float4*)(_p0 + 4);                     \
    DST[1][0] = *(const float4*)_p1;                           \
    DST[1][1] = *(const float4*)(_p1 + 4);                     \
} while (0)

#define LOADB(K, DST) do {                                     \
    _Pragma("unroll")                                          \
    for (int _jt = 0; _jt < 4; _jt++)                          \
        DST[_jt] = bb[(size_t)(K) * 1024 + _jt * 64];          \
} while (0)

__global__ __launch_bounds__(256, 2) void k_scores(
    const float* __restrict__ enc, const unsigned short* __restrict__ Bfrag,
    const float* __restrict__ u, const float* __restrict__ v_w,
    const float* __restrict__ v_b, const int* __restrict__ lengths,
    float* __restrict__ scores)
{
    __shared__ float sPart[4][64];

    const int b   = blockIdx.y;
    const int s0  = blockIdx.x * 64;
    const int len = lengths[b];
    if (s0 >= len) return;

    const int tid = threadIdx.x;
    const int w   = tid >> 6;     // wave 0..3
    const int l   = tid & 63;     // lane

    const float* a0p = enc + ((size_t)b * S + s0 + (l & 31)) * KE + ((l >> 5) << 3);
    const float* a1p = a0p + (size_t)32 * KE;
    const short8* bb = (const short8*)Bfrag + (w * 4) * 64 + l;

    f32x16 acc[2][4];
    #pragma unroll
    for (int mt = 0; mt < 2; mt++)
        #pragma unroll
        for (int jt = 0; jt < 4; jt++)
            #pragma unroll
            for (int e = 0; e < 16; e++) acc[mt][jt][e] = 0.f;

    float4 pa[4][2][2];   // [stage][mt][half] : A prefetch distance 4
    short8 pb[2][4];      // [stage][jt]       : B prefetch distance 2
    LOADA(0, pa[0]);
    LOADA(1, pa[1]);
    LOADA(2, pa[2]);
    LOADA(3, pa[3]);
    LOADB(0, pb[0]);
    LOADB(1, pb[1]);

    #pragma unroll 4
    for (int k16 = 0; k16 < 64; ++k16) {
        const int st = k16 & 3;
        const int bp = k16 & 1;
        short8 a0 = pack8(pa[st][0][0], pa[st][0][1]);
        short8 a1 = pack8(pa[st][1][0], pa[st][1][1]);
        LOADA((k16 + 4) & 63, pa[st]);          // refill A stage (distance 4)
        #pragma unroll
        for (int jt = 0; jt < 4; jt++) {
            acc[0][jt] = __builtin_amdgcn_mfma_f32_32x32x16_bf16(a0, pb[bp][jt], acc[0][jt], 0, 0, 0);
            acc[1][jt] = __builtin_amdgcn_mfma_f32_32x32x16_bf16(a1, pb[bp][jt], acc[1][jt], 0, 0, 0);
        }
        LOADB((k16 + 2) & 63, pb[bp]);          // refill B stage (distance 2)
    }

    // ---- epilogue: score_part = sum_d v[d]*tanh(pre + u[d]) ----
    // C/D layout (32x32): col = lane&31, row = (reg&3) + 8*(reg>>2) + 4*(lane>>5)
    float vv[4], uu[4];
    const float* ub = u + b * D;
    #pragma unroll
    for (int jt = 0; jt < 4; jt++) {
        int d = w * 128 + jt * 32 + (l & 31);
        vv[jt] = v_w[d];
        uu[jt] = ub[d];
    }
    float red[2][16];
    #pragma unroll
    for (int mt = 0; mt < 2; mt++)
        #pragma unroll
        for (int r = 0; r < 16; r++) {
            float s = 0.f;
            #pragma unroll
            for (int jt = 0; jt < 4; jt++)
                s += vv[jt] * tanh_fast(acc[mt][jt][r] + uu[jt]);
            red[mt][r] = s;
        }
    #pragma unroll
    for (int off = 16; off >= 1; off >>= 1)
        #pragma unroll
        for (int mt = 0; mt < 2; mt++)
            #pragma unroll
            for (int r = 0; r < 16; r++)
                red[mt][r] += __shfl_xor(red[mt][r], off);
    if ((l & 31) == 0) {
        int hb = (l >> 5) * 4;
        #pragma unroll
        for (int mt = 0; mt < 2; mt++)
            #pragma unroll
            for (int r = 0; r < 16; r++)
                sPart[w][mt * 32 + (r & 3) + 8 * (r >> 2) + hb] = red[mt][r];
    }
    __syncthreads();
    if (tid < 64)
        scores[b * S + s0 + tid] =
            sPart[0][tid] + sPart[1][tid] + sPart[2][tid] + sPart[3][tid] + v_b[0];
}

// ---------- kernel 3: masked softmax over s < len ----------
__global__ void k_softmax(const float* __restrict__ scores,
                          const int* __restrict__ lengths,
                          float* __restrict__ energy) {
    const int b = blockIdx.x;
    const int len = lengths[b];
    const int tid = threadIdx.x;
    const int lane = tid & 63, wave = tid >> 6;
    __shared__ float red[4];
    const float* sc = scores + b * S;

    float m = -INFINITY;
    for (int s = tid; s < len; s += 256) m = fmaxf(m, sc[s]);
    #pragma unroll
    for (int off = 32; off >= 1; off >>= 1) m = fmaxf(m, __shfl_xor(m, off));
    if (lane == 0) red[wave] = m;
    __syncthreads();
    m = fmaxf(fmaxf(red[0], red[1]), fmaxf(red[2], red[3]));
    __syncthreads();

    float sum = 0.f;
    for (int s = tid; s < len; s += 256) sum += __expf(sc[s] - m);
    #pragma unroll
    for (int off = 32; off >= 1; off >>= 1) sum += __shfl_xor(sum, off);
    if (lane == 0) red[wave] = sum;
    __syncthreads();
    float inv = 1.f / (red[0] + red[1] + red[2] + red[3]);

    for (int s = tid; s < len; s += 256) energy[b * S + s] = __expf(sc[s] - m) * inv;
}

// ---------- kernel 4: context[b][e] = sum_s energy[b][s]*enc[b][s][e] ----------
__global__ void k_context(const float* __restrict__ enc,
                          const float* __restrict__ energy,
                          const int* __restrict__ lengths,
                          float* __restrict__ out) {
    const int b = blockIdx.y;
    const int len = lengths[b];
    const int s0 = blockIdx.x * 128;
    if (s0 >= len) return;
    const int s1 = min(s0 + 128, len);
    const int tid = threadIdx.x;                 // 256 threads x float4 = 1024 e
    const float4* encb = (const float4*)(enc + (size_t)b * S * KE);
    const float* en = energy + b * S;
    float4 acc[8];
    #pragma unroll
    for (int i = 0; i < 8; i++) acc[i] = make_float4(0.f, 0.f, 0.f, 0.f);
    int s = s0;
    for (; s + 8 <= s1; s += 8) {
        #pragma unroll
        for (int i = 0; i < 8; i++) {
            float wgt = en[s + i];
            float4 v = encb[(size_t)(s + i) * 256 + tid];
            acc[i].x += wgt * v.x; acc[i].y += wgt * v.y;
            acc[i].z += wgt * v.z; acc[i].w += wgt * v.w;
        }
    }
    for (; s < s1; s++) {
        float wgt = en[s];
        float4 v = encb[(size_t)s * 256 + tid];
        acc[0].x += wgt * v.x; acc[0].y += wgt * v.y;
        acc[0].z += wgt * v.z; acc[0].w += wgt * v.w;
    }
    #pragma unroll
    for (int i = 1; i < 8; i++) {
        acc[0].x += acc[i].x; acc[0].y += acc[i].y;
        acc[0].z += acc[i].z; acc[0].w += acc[i].w;
    }
    float* o = out + b * KE + tid * 4;
    atomicAdd(o + 0, acc[0].x);
    atomicAdd(o + 1, acc[0].y);
    atomicAdd(o + 2, acc[0].z);
    atomicAdd(o + 3, acc[0].w);
}

extern "C" void kernel_launch(void* const* d_in, const int* in_sizes, int n_in,
                              void* d_out, int out_size, void* d_ws, size_t ws_size,
                              hipStream_t stream) {
    const float* enc    = (const float*)d_in[0];
    const float* hidden = (const float*)d_in[1];
    const int*   lengths= (const int*)d_in[2];
    const float* attn_w = (const float*)d_in[3];
    const float* attn_b = (const float*)d_in[4];
    const float* v_w    = (const float*)d_in[5];
    const float* v_b    = (const float*)d_in[6];
    float* out = (float*)d_out;

    // workspace layout (fp32 elements)
    float* ws     = (float*)d_ws;
    float* u      = ws;                     // 16384 floats
    float* scores = u + B * D;              // 65536 floats
    float* energy = scores + B * S;         // 65536 floats
    unsigned short* Bf = (unsigned short*)(energy + B * S);  // 524288 bf16 = 1MB, 16B-aligned

    (void)hipMemsetAsync(d_out, 0, (size_t)out_size * sizeof(float), stream);
    k_prep  <<<dim3(320), 256, 0, stream>>>(attn_w, hidden, attn_b, Bf, u);
    k_scores<<<dim3(S / 64, B), 256, 0, stream>>>(enc, Bf, u, v_w, v_b, lengths, scores);
    k_softmax<<<dim3(B), 256, 0, stream>>>(scores, lengths, energy);
    k_context<<<dim3(16, B), 256, 0, stream>>>(enc, energy, lengths, out);
}

// Round 6
// 454.665 us; speedup vs baseline: 2.1359x; 1.1565x over previous
//
#include <hip/hip_runtime.h>
#include <hip/hip_bf16.h>
#include <math.h>

typedef __attribute__((ext_vector_type(4))) short short4v;
typedef __attribute__((ext_vector_type(8))) short short8;
typedef __attribute__((ext_vector_type(16))) float f32x16;

static constexpr int B  = 32;
static constexpr int S  = 2048;
static constexpr int D  = 512;
static constexpr int KE = 1024;   // encoder feature dim = 2*ENC_H
static constexpr int IN = 1536;   // D + KE

__device__ __forceinline__ unsigned pk2(float lo, float hi) {
    __hip_bfloat162 t = __float22bfloat162_rn(make_float2(lo, hi));
    unsigned u;
    __builtin_memcpy(&u, &t, 4);
    return u;
}

// float4 -> 4 bf16 (8 B)
__device__ __forceinline__ short4v pack4(float4 f) {
    unsigned u2[2] = { pk2(f.x, f.y), pk2(f.z, f.w) };
    short4v r;
    __builtin_memcpy(&r, u2, 8);
    return r;
}

// pack 8 fp32 -> short8 bf16
__device__ __forceinline__ short8 pack8(float4 f0, float4 f1) {
    unsigned u[4] = { pk2(f0.x, f0.y), pk2(f0.z, f0.w), pk2(f1.x, f1.y), pk2(f1.z, f1.w) };
    short8 r;
    __builtin_memcpy(&r, u, 16);
    return r;
}

__device__ __forceinline__ short8 cat44(short4v lo, short4v hi) {
    short8 r;
    __builtin_memcpy(&r, &lo, 8);
    __builtin_memcpy(((char*)&r) + 8, &hi, 8);
    return r;
}

// fast tanh via exp: (e^2x - 1)/(e^2x + 1)
__device__ __forceinline__ float tanh_fast(float x) {
    float e = __expf(2.0f * x);
    return (e - 1.0f) * __builtin_amdgcn_rcpf(e + 1.0f);
}

// ---------- kernel 0: fused prep ----------
// blocks [0,256): pack enc-part of attn_w into bf16 MFMA-B-fragment order
//   Bf layout: element (d,k) -> short8 index ((k>>4)*16 + (d>>5))*64 + (d&31) + ((k>>3)&1)*32, slot j=k&7
// blocks [256,320): u[b][d] = hidden[b]·attn_w[d,0:512] + attn_b[d]
__global__ void k_prep(const float* __restrict__ attn_w,
                       const float* __restrict__ hidden,
                       const float* __restrict__ attn_b,
                       unsigned short* __restrict__ Bf,
                       float* __restrict__ u) {
    if (blockIdx.x < 256) {
        int o = blockIdx.x * 256 + threadIdx.x;   // short8 index, 65536 total
        int l6  = o & 63;
        int grp = o >> 6;
        int d = (grp & 15) * 32 + (l6 & 31);
        int k = (grp >> 4) * 16 + (l6 >> 5) * 8;
        const float* src = attn_w + (size_t)d * IN + 512 + k;
        float4 f0 = *(const float4*)src;
        float4 f1 = *(const float4*)(src + 4);
        ((short8*)Bf)[o] = pack8(f0, f1);
    } else {
        int gid = (blockIdx.x - 256) * 256 + threadIdx.x;   // 16384 total
        int b = gid >> 9;
        int d = gid & (D - 1);
        const float* h = hidden + b * D;
        const float* w = attn_w + (size_t)d * IN;
        float acc = attn_b[d];
        for (int k = 0; k < D; k += 4) {
            float4 hv = *(const float4*)(h + k);
            float4 wv = *(const float4*)(w + k);
            acc += hv.x * wv.x + hv.y * wv.y + hv.z * wv.z + hv.w * wv.w;
        }
        u[gid] = acc;
    }
}

// ---------- kernel 2: scores via bf16 MFMA, LDS-transposed A, global B ----------
// block: 64 s x 512 d, 4 waves; wave w owns d-slice [w*128,(w+1)*128).
// K-chunks of 64: coalesced global float4 loads -> bf16 -> padded LDS tile (dbuf).
// LDS tile: row m (0..63), 64 bf16 of k; row stride 19 short4-units (152 B):
//   write lanes 2-way banked (free), b64 frag reads conflict-free.
#define LOADB(K, DST) do {                                     \
    _Pragma("unroll")                                          \
    for (int _jt = 0; _jt < 4; _jt++)                          \
        DST[_jt] = bb[(size_t)(K) * 1024 + _jt * 64];          \
} while (0)

__global__ __launch_bounds__(256, 2) void k_scores(
    const float* __restrict__ enc, const unsigned short* __restrict__ Bfrag,
    const float* __restrict__ u, const float* __restrict__ v_w,
    const float* __restrict__ v_b, const int* __restrict__ lengths,
    float* __restrict__ scores)
{
    __shared__ short4v ldsA[2][64 * 19];   // 2 x 9728 B
    __shared__ float sPart[4][64];

    const int b   = blockIdx.y;
    const int s0  = blockIdx.x * 64;
    const int len = lengths[b];
    if (s0 >= len) return;

    const int tid = threadIdx.x;
    const int w   = tid >> 6;     // wave 0..3
    const int l   = tid & 63;     // lane

    const float* encb = enc + ((size_t)b * S + s0) * KE;
    // staging: sweep i handles row mr+16*i, float4-col c (16 threads/row)
    const int mr = tid >> 4;
    const int cw = tid & 15;
    const float* aG = encb + (size_t)mr * KE + cw * 4;
    const int wbase = mr * 19 + cw;        // ldsA unit index for this thread's writes (+16*i*19)

    const short8* bb = (const short8*)Bfrag + (w * 4) * 64 + l;

    f32x16 acc[2][4];
    #pragma unroll
    for (int mt = 0; mt < 2; mt++)
        #pragma unroll
        for (int jt = 0; jt < 4; jt++)
            #pragma unroll
            for (int e = 0; e < 16; e++) acc[mt][jt][e] = 0.f;

    short8 pb[2][4];
    LOADB(0, pb[0]);
    LOADB(1, pb[1]);

    // stage chunk 0 into buf 0
    {
        float4 g[4];
        #pragma unroll
        for (int i = 0; i < 4; i++) g[i] = *(const float4*)(aG + (size_t)i * 16 * KE);
        #pragma unroll
        for (int i = 0; i < 4; i++) ldsA[0][wbase + i * 16 * 19] = pack4(g[i]);
    }
    __syncthreads();

    // frag read base: unit = m*19 + t2*4 + (l>>5)*2, m = (l&31)+32*mt
    const int rb0 = (l & 31) * 19 + (l >> 5) * 2;
    const int rb1 = rb0 + 32 * 19;

    #pragma unroll 1
    for (int c = 0; c < 16; ++c) {
        const int buf = c & 1;
        const int cn  = (c + 1) & 15;
        // global prefetch of chunk c+1 (consumed after syncA)
        float4 g[4];
        #pragma unroll
        for (int i = 0; i < 4; i++)
            g[i] = *(const float4*)(aG + (size_t)i * 16 * KE + cn * 64);
        // compute chunk c
        #pragma unroll
        for (int t2 = 0; t2 < 4; ++t2) {
            const short4v* base = &ldsA[buf][t2 * 4];
            short8 a0 = cat44(base[rb0], base[rb0 + 1]);
            short8 a1 = cat44(base[rb1], base[rb1 + 1]);
            const int bp = t2 & 1;
            #pragma unroll
            for (int jt = 0; jt < 4; jt++) {
                acc[0][jt] = __builtin_amdgcn_mfma_f32_32x32x16_bf16(a0, pb[bp][jt], acc[0][jt], 0, 0, 0);
                acc[1][jt] = __builtin_amdgcn_mfma_f32_32x32x16_bf16(a1, pb[bp][jt], acc[1][jt], 0, 0, 0);
            }
            LOADB((c * 4 + t2 + 2) & 63, pb[bp]);
        }
        __syncthreads();
        #pragma unroll
        for (int i = 0; i < 4; i++)
            ldsA[buf ^ 1][wbase + i * 16 * 19] = pack4(g[i]);
        __syncthreads();
    }

    // ---- epilogue: score_part = sum_d v[d]*tanh(pre + u[d]) ----
    // C/D layout (32x32): col = lane&31, row = (reg&3) + 8*(reg>>2) + 4*(lane>>5)
    float vv[4], uu[4];
    const float* ub = u + b * D;
    #pragma unroll
    for (int jt = 0; jt < 4; jt++) {
        int d = w * 128 + jt * 32 + (l & 31);
        vv[jt] = v_w[d];
        uu[jt] = ub[d];
    }
    float red[2][16];
    #pragma unroll
    for (int mt = 0; mt < 2; mt++)
        #pragma unroll
        for (int r = 0; r < 16; r++) {
            float s = 0.f;
            #pragma unroll
            for (int jt = 0; jt < 4; jt++)
                s += vv[jt] * tanh_fast(acc[mt][jt][r] + uu[jt]);
            red[mt][r] = s;
        }
    #pragma unroll
    for (int off = 16; off >= 1; off >>= 1)
        #pragma unroll
        for (int mt = 0; mt < 2; mt++)
            #pragma unroll
            for (int r = 0; r < 16; r++)
                red[mt][r] += __shfl_xor(red[mt][r], off);
    if ((l & 31) == 0) {
        int hb = (l >> 5) * 4;
        #pragma unroll
        for (int mt = 0; mt < 2; mt++)
            #pragma unroll
            for (int r = 0; r < 16; r++)
                sPart[w][mt * 32 + (r & 3) + 8 * (r >> 2) + hb] = red[mt][r];
    }
    __syncthreads();
    if (tid < 64)
        scores[b * S + s0 + tid] =
            sPart[0][tid] + sPart[1][tid] + sPart[2][tid] + sPart[3][tid] + v_b[0];
}

// ---------- kernel 3: masked softmax over s < len ----------
__global__ void k_softmax(const float* __restrict__ scores,
                          const int* __restrict__ lengths,
                          float* __restrict__ energy) {
    const int b = blockIdx.x;
    const int len = lengths[b];
    const int tid = threadIdx.x;
    const int lane = tid & 63, wave = tid >> 6;
    __shared__ float red[4];
    const float* sc = scores + b * S;

    float m = -INFINITY;
    for (int s = tid; s < len; s += 256) m = fmaxf(m, sc[s]);
    #pragma unroll
    for (int off = 32; off >= 1; off >>= 1) m = fmaxf(m, __shfl_xor(m, off));
    if (lane == 0) red[wave] = m;
    __syncthreads();
    m = fmaxf(fmaxf(red[0], red[1]), fmaxf(red[2], red[3]));
    __syncthreads();

    float sum = 0.f;
    for (int s = tid; s < len; s += 256) sum += __expf(sc[s] - m);
    #pragma unroll
    for (int off = 32; off >= 1; off >>= 1) sum += __shfl_xor(sum, off);
    if (lane == 0) red[wave] = sum;
    __syncthreads();
    float inv = 1.f / (red[0] + red[1] + red[2] + red[3]);

    for (int s = tid; s < len; s += 256) energy[b * S + s] = __expf(sc[s] - m) * inv;
}

// ---------- kernel 4: context[b][e] = sum_s energy[b][s]*enc[b][s][e] ----------
__global__ void k_context(const float* __restrict__ enc,
                          const float* __restrict__ energy,
                          const int* __restrict__ lengths,
                          float* __restrict__ out) {
    const int b = blockIdx.y;
    const int len = lengths[b];
    const int s0 = blockIdx.x * 128;
    if (s0 >= len) return;
    const int s1 = min(s0 + 128, len);
    const int tid = threadIdx.x;                 // 256 threads x float4 = 1024 e
    const float4* encb = (const float4*)(enc + (size_t)b * S * KE);
    const float* en = energy + b * S;
    float4 acc[8];
    #pragma unroll
    for (int i = 0; i < 8; i++) acc[i] = make_float4(0.f, 0.f, 0.f, 0.f);
    int s = s0;
    for (; s + 8 <= s1; s += 8) {
        #pragma unroll
        for (int i = 0; i < 8; i++) {
            float wgt = en[s + i];
            float4 v = encb[(size_t)(s + i) * 256 + tid];
            acc[i].x += wgt * v.x; acc[i].y += wgt * v.y;
            acc[i].z += wgt * v.z; acc[i].w += wgt * v.w;
        }
    }
    for (; s < s1; s++) {
        float wgt = en[s];
        float4 v = encb[(size_t)s * 256 + tid];
        acc[0].x += wgt * v.x; acc[0].y += wgt * v.y;
        acc[0].z += wgt * v.z; acc[0].w += wgt * v.w;
    }
    #pragma unroll
    for (int i = 1; i < 8; i++) {
        acc[0].x += acc[i].x; acc[0].y += acc[i].y;
        acc[0].z += acc[i].z; acc[0].w += acc[i].w;
    }
    float* o = out + b * KE + tid * 4;
    atomicAdd(o + 0, acc[0].x);
    atomicAdd(o + 1, acc[0].y);
    atomicAdd(o + 2, acc[0].z);
    atomicAdd(o + 3, acc[0].w);
}

extern "C" void kernel_launch(void* const* d_in, const int* in_sizes, int n_in,
                              void* d_out, int out_size, void* d_ws, size_t ws_size,
                              hipStream_t stream) {
    const float* enc    = (const float*)d_in[0];
    const float* hidden = (const float*)d_in[1];
    const int*   lengths= (const int*)d_in[2];
    const float* attn_w = (const float*)d_in[3];
    const float* attn_b = (const float*)d_in[4];
    const float* v_w    = (const float*)d_in[5];
    const float* v_b    = (const float*)d_in[6];
    float* out = (float*)d_out;

    // workspace layout (fp32 elements)
    float* ws     = (float*)d_ws;
    float* u      = ws;                     // 16384 floats
    float* scores = u + B * D;              // 65536 floats
    float* energy = scores + B * S;         // 65536 floats
    unsigned short* Bf = (unsigned short*)(energy + B * S);  // 524288 bf16 = 1MB, 16B-aligned

    (void)hipMemsetAsync(d_out, 0, (size_t)out_size * sizeof(float), stream);
    k_prep  <<<dim3(320), 256, 0, stream>>>(attn_w, hidden, attn_b, Bf, u);
    k_scores<<<dim3(S / 64, B), 256, 0, stream>>>(enc, Bf, u, v_w, v_b, lengths, scores);
    k_softmax<<<dim3(B), 256, 0, stream>>>(scores, lengths, energy);
    k_context<<<dim3(16, B), 256, 0, stream>>>(enc, energy, lengths, out);
}